// Round 12
// baseline (263.977 us; speedup 1.0000x reference)
//
#include <hip/hip_runtime.h>
#include <math.h>

#define D 64
#define NC 40

// CSR-build bucket sort parameters (N=100000, E=800000)
#define RPB 512
#define BSHIFT 9
#define NBUCK 200
#define CHUNK 4000
#define CAP 5400

typedef __fp16 half2_t __attribute__((ext_vector_type(2)));
typedef _Float16 h8 __attribute__((ext_vector_type(8)));
typedef float f4 __attribute__((ext_vector_type(4)));

__device__ __forceinline__ unsigned pack_f16(float a, float b) {
    half2_t h = __builtin_amdgcn_cvt_pkrtz(a, b);
    return __builtin_bit_cast(unsigned, h);
}

// Branchless pair-packed gather for 8 rows of one wave (8 indep streams).
__device__ __forceinline__ void gather8_packed(
    const __fp16* __restrict__ t, const int* __restrict__ rowptr,
    const int* __restrict__ col, int rowA, int N, int lane,
    float a0[8], float a1[8])
{
    int m = lane & 31;
    bool low = lane < 32;
    int begr[8], degr[8], colv[8], pairs[8];
#pragma unroll
    for (int i = 0; i < 8; ++i) {
        int row = rowA + i;
        int rc = min(row, N - 1);
        int bg = __builtin_amdgcn_readfirstlane(rowptr[rc]);
        int en = __builtin_amdgcn_readfirstlane(rowptr[rc + 1]);
        int dg = (row < N) ? (en - bg) : 0;
        begr[i] = bg; degr[i] = dg;
        int cl = min(dg, 64);
        colv[i] = (lane < cl) ? col[bg + lane] : 0;  // pad -> row 0 (cached)
        pairs[i] = cl >> 1;
        a0[i] = 0.f; a1[i] = 0.f;
    }
    int minp = pairs[0], maxp = pairs[0];
#pragma unroll
    for (int i = 1; i < 8; ++i) { minp = min(minp, pairs[i]); maxp = max(maxp, pairs[i]); }
    int q = 0;
#pragma unroll 2
    for (; q < minp; ++q) {                        // unmasked common part
        float v0[8], v1[8];
#pragma unroll
        for (int i = 0; i < 8; ++i) {
            int ja = __builtin_amdgcn_readlane(colv[i], 2 * q);
            int jb = __builtin_amdgcn_readlane(colv[i], 2 * q + 1);
            int j = low ? ja : jb;
            unsigned pv = *(const unsigned*)&t[((size_t)j << 6) + 2 * m];
            half2_t hp = __builtin_bit_cast(half2_t, pv);
            v0[i] = (float)hp.x; v1[i] = (float)hp.y;
        }
#pragma unroll
        for (int i = 0; i < 8; ++i) { a0[i] += v0[i]; a1[i] += v1[i]; }
    }
    for (; q < maxp; ++q) {                        // masked remainder
        float v0[8], v1[8], mk[8];
#pragma unroll
        for (int i = 0; i < 8; ++i) {
            int ja = __builtin_amdgcn_readlane(colv[i], 2 * q);
            int jb = __builtin_amdgcn_readlane(colv[i], 2 * q + 1);
            int j = low ? ja : jb;
            unsigned pv = *(const unsigned*)&t[((size_t)j << 6) + 2 * m];
            half2_t hp = __builtin_bit_cast(half2_t, pv);
            v0[i] = (float)hp.x; v1[i] = (float)hp.y;
            mk[i] = (q < pairs[i]) ? 1.f : 0.f;
        }
#pragma unroll
        for (int i = 0; i < 8; ++i) {
            a0[i] = fmaf(mk[i], v0[i], a0[i]);
            a1[i] = fmaf(mk[i], v1[i], a1[i]);
        }
    }
#pragma unroll
    for (int i = 0; i < 8; ++i) {
        int cl = min(degr[i], 64);
        if (cl & 1) {                              // uniform branch, odd tail
            int j = __builtin_amdgcn_readlane(colv[i], cl - 1);
            unsigned pv = *(const unsigned*)&t[((size_t)j << 6) + 2 * m];
            half2_t hp = __builtin_bit_cast(half2_t, pv);
            float mk2 = low ? 1.f : 0.f;           // count once
            a0[i] = fmaf(mk2, (float)hp.x, a0[i]);
            a1[i] = fmaf(mk2, (float)hp.y, a1[i]);
        }
        for (int p = begr[i] + 64; p < begr[i] + degr[i]; ++p) {  // deg>64
            int j = __builtin_amdgcn_readfirstlane(col[p]);
            unsigned pv = *(const unsigned*)&t[((size_t)j << 6) + 2 * m];
            half2_t hp = __builtin_bit_cast(half2_t, pv);
            float mk2 = low ? 1.f : 0.f;
            a0[i] = fmaf(mk2, (float)hp.x, a0[i]);
            a1[i] = fmaf(mk2, (float)hp.y, a1[i]);
        }
    }
#pragma unroll
    for (int i = 0; i < 8; ++i) {                  // combine halves
        a0[i] += __shfl_xor(a0[i], 32, 64);
        a1[i] += __shfl_xor(a1[i], 32, 64);
    }
}

// ---- CSR build: two-pass LDS-staged bucket sort ------------------------

__global__ __launch_bounds__(256) void part1_kernel(
    const int* __restrict__ src, const int* __restrict__ dst, int E,
    unsigned* __restrict__ staging, int* __restrict__ cursors)
{
    __shared__ int hist[NBUCK], off[NBUCK], cnt2[NBUCK], rbase[NBUCK];
    __shared__ int tmp[256];
    __shared__ unsigned packed[CHUNK];
    __shared__ unsigned char bof[CHUNK];
    int tid = threadIdx.x;
    int beg = blockIdx.x * CHUNK;
    int n = min(CHUNK, E - beg);
    for (int i = tid; i < NBUCK; i += 256) { hist[i] = 0; cnt2[i] = 0; }
    __syncthreads();
    for (int i = tid; i < n; i += 256) {
        int d = dst[beg + i];
        atomicAdd(&hist[d >> BSHIFT], 1);
    }
    __syncthreads();
    int v = (tid < NBUCK) ? hist[tid] : 0;
    tmp[tid] = v;
    __syncthreads();
    for (int o = 1; o < 256; o <<= 1) {
        int t = (tid >= o) ? tmp[tid - o] : 0;
        __syncthreads();
        tmp[tid] += t;
        __syncthreads();
    }
    if (tid < NBUCK) {
        off[tid] = tmp[tid] - v;
        rbase[tid] = v ? atomicAdd(&cursors[tid], v) : 0;
    }
    __syncthreads();
    for (int i = tid; i < n; i += 256) {
        int d = dst[beg + i];
        int s = src[beg + i];
        int b = d >> BSHIFT;
        int p = off[b] + atomicAdd(&cnt2[b], 1);
        packed[p] = ((unsigned)(d & (RPB - 1)) << 17) | (unsigned)s;
        bof[p] = (unsigned char)b;
    }
    __syncthreads();
    for (int i = tid; i < n; i += 256) {
        int b = bof[i];
        int idx = rbase[b] + (i - off[b]);
        if (idx < CAP) staging[(size_t)b * CAP + idx] = packed[i];
    }
}

__global__ __launch_bounds__(256) void part2_kernel(
    const unsigned* __restrict__ staging, const int* __restrict__ cursors,
    int* __restrict__ rowptr, float* __restrict__ dinv, int* __restrict__ col,
    int N, int E)
{
    __shared__ int hist[RPB], off[RPB], cur[RPB];
    __shared__ int tmp[256];
    __shared__ int colstage[CAP];
    __shared__ int sb[2];
    int tid = threadIdx.x;
    int b = blockIdx.x;
    int v = (tid < NBUCK) ? cursors[tid] : 0;
    tmp[tid] = v;
    __syncthreads();
    for (int o = 1; o < 256; o <<= 1) {
        int t = (tid >= o) ? tmp[tid - o] : 0;
        __syncthreads();
        tmp[tid] += t;
        __syncthreads();
    }
    if (tid == 0) { sb[0] = (b ? tmp[b - 1] : 0); sb[1] = min(cursors[b], CAP); }
    for (int i = tid; i < RPB; i += 256) { hist[i] = 0; cur[i] = 0; }
    __syncthreads();
    int base = sb[0], nE = sb[1];
    const unsigned* stg = staging + (size_t)b * CAP;
    for (int i = tid; i < nE; i += 256) atomicAdd(&hist[stg[i] >> 17], 1);
    __syncthreads();
    int a0 = hist[2 * tid], a1 = hist[2 * tid + 1];
    int ps = a0 + a1;
    tmp[tid] = ps;
    __syncthreads();
    for (int o = 1; o < 256; o <<= 1) {
        int t = (tid >= o) ? tmp[tid - o] : 0;
        __syncthreads();
        tmp[tid] += t;
        __syncthreads();
    }
    int pex = tmp[tid] - ps;
    off[2 * tid] = pex;
    off[2 * tid + 1] = pex + a0;
    __syncthreads();
    int r0 = b * RPB;
    for (int r = tid; r < RPB; r += 256) {
        int row = r0 + r;
        if (row < N) {
            rowptr[row] = base + off[r];
            dinv[row] = rsqrtf((float)hist[r] + 1.0f);  // +1 self-loop
        }
    }
    if (b == NBUCK - 1 && tid == 0) rowptr[N] = E;
    for (int i = tid; i < nE; i += 256) {
        unsigned pv = stg[i];
        int row = pv >> 17;
        int p = off[row] + atomicAdd(&cur[row], 1);
        colstage[p] = (int)(pv & 0x1FFFFu);
    }
    __syncthreads();
    for (int i = tid; i < nE; i += 256) col[base + i] = colstage[i];
}

// ---- Weight packing (also zeroes cursors) -------------------------------
__global__ void pack_weights2(const float* __restrict__ W0, const float* __restrict__ W1,
                              const float* __restrict__ W2, const float* __restrict__ Wc,
                              __fp16* __restrict__ pB0, __fp16* __restrict__ pB1,
                              __fp16* __restrict__ pB2, __fp16* __restrict__ pBc,
                              int* __restrict__ cursors) {
    int i = blockIdx.x * blockDim.x + threadIdx.x;
    if (i < NBUCK) cursors[i] = 0;
    if (i < 4096) {
        int j = i & 7, lane = (i >> 3) & 63, st = i >> 9;  // st = s*4+t
        int s = st >> 2, t = st & 3;
        int k = 32 * s + ((lane >> 4) * 8 + j);
        int n = 16 * t + (lane & 15);
        pB0[i] = (__fp16)W0[k * D + n];
        pB1[i] = (__fp16)W1[k * D + n];
        pB2[i] = (__fp16)W2[k * D + n];
    }
    if (i < 3072) {
        int j = i & 7, lane = (i >> 3) & 63, st = i >> 9;  // st = s*3+t
        int s = st / 3, t = st % 3;
        int k = 32 * s + ((lane >> 4) * 8 + j);
        int n = 16 * t + (lane & 15);
        pBc[i] = (n < NC) ? (__fp16)Wc[k * NC + n] : (__fp16)0.f;
    }
}

// ---- Compute -----------------------------------------------------------

// t = dinv * (x @ W0) via MFMA with LDS-staged A (coalesced x loads).
__global__ __launch_bounds__(256) void transform_mfma(
    const float* __restrict__ x, const float* __restrict__ dinv,
    const __fp16* __restrict__ pB0, __fp16* __restrict__ t, int N)
{
    __shared__ __align__(16) __fp16 hts[16 * 64];
    int w = threadIdx.x >> 6, lane = threadIdx.x & 63;
    int tileRow = blockIdx.x * 16;
#pragma unroll
    for (int i = 0; i < 4; ++i) {
        int row = tileRow + w * 4 + i;
        float v = (row < N) ? x[(size_t)row * D + lane] : 0.f;  // coalesced
        hts[(w * 4 + i) * 64 + lane] = (__fp16)v;
    }
    __syncthreads();
    int quad = lane >> 4, m16 = lane & 15;
    h8 fa0 = *(const h8*)&hts[m16 * 64 + 0 + quad * 8];   // A[m][k], k=quad*8+j
    h8 fa1 = *(const h8*)&hts[m16 * 64 + 32 + quad * 8];
    h8 fb0 = *(const h8*)&pB0[(size_t)(0 * 4 + w) * 512 + lane * 8];
    h8 fb1 = *(const h8*)&pB0[(size_t)(1 * 4 + w) * 512 + lane * 8];
    f4 c = {0.f, 0.f, 0.f, 0.f};
    c = __builtin_amdgcn_mfma_f32_16x16x32_f16(fa0, fb0, c, 0, 0, 0);
    c = __builtin_amdgcn_mfma_f32_16x16x32_f16(fa1, fb1, c, 0, 0, 0);
#pragma unroll
    for (int r = 0; r < 4; ++r) {
        int mrow = quad * 4 + r;           // C/D: col=lane&15, row=quad*4+reg
        int grow = tileRow + mrow;
        if (grow < N) t[(size_t)grow * D + w * 16 + m16] = (__fp16)(c[r] * dinv[grow]);
    }
}

// Block = 4 waves = 32-row tile, 8 rows/wave gather -> LDS -> MFMA h@W.
__global__ __launch_bounds__(256) void fused_layer_mfma(
    const __fp16* __restrict__ t, const int* __restrict__ rowptr,
    const int* __restrict__ col, const float* __restrict__ dinv,
    const float* __restrict__ b, const __fp16* __restrict__ pB,
    __fp16* __restrict__ tn, int N)
{
    __shared__ __align__(16) __fp16 hts[32 * 64];
    __shared__ float dts[32];
    int w = threadIdx.x >> 6, lane = threadIdx.x & 63;
    int tileRow = blockIdx.x * 32;
    int rowA = tileRow + w * 8;
    int m = lane & 31;
    float a0[8], a1[8];
    gather8_packed(t, rowptr, col, rowA, N, lane, a0, a1);
    float2 bb = ((const float2*)b)[m];
#pragma unroll
    for (int i = 0; i < 8; ++i) {
        int row = rowA + i;
        float h0 = 0.f, h1 = 0.f, dv = 0.f;
        if (row < N) {                         // uniform
            dv = dinv[row];
            unsigned pv = *(const unsigned*)&t[((size_t)row << 6) + 2 * m];
            half2_t hp = __builtin_bit_cast(half2_t, pv);   // self-loop
            h0 = fmaxf(fmaf(dv, a0[i] + (float)hp.x, bb.x), 0.f);
            h1 = fmaxf(fmaf(dv, a1[i] + (float)hp.y, bb.y), 0.f);
        }
        if (lane < 32) {
            ((unsigned*)hts)[(w * 8 + i) * 32 + m] = pack_f16(h0, h1);
            if (lane == 0) dts[w * 8 + i] = dv;
        }
    }
    __syncthreads();
    int quad = lane >> 4, m16 = lane & 15;
    h8 fb0 = *(const h8*)&pB[(size_t)(0 * 4 + w) * 512 + lane * 8];
    h8 fb1 = *(const h8*)&pB[(size_t)(1 * 4 + w) * 512 + lane * 8];
#pragma unroll
    for (int sub = 0; sub < 2; ++sub) {
        int lr = sub * 16 + m16;
        h8 fa0 = *(const h8*)&hts[lr * 64 + 0 + quad * 8];   // A[m][k]
        h8 fa1 = *(const h8*)&hts[lr * 64 + 32 + quad * 8];
        f4 c = {0.f, 0.f, 0.f, 0.f};
        c = __builtin_amdgcn_mfma_f32_16x16x32_f16(fa0, fb0, c, 0, 0, 0);
        c = __builtin_amdgcn_mfma_f32_16x16x32_f16(fa1, fb1, c, 0, 0, 0);
#pragma unroll
        for (int r = 0; r < 4; ++r) {
            int mrow = sub * 16 + quad * 4 + r;   // C/D: col=lane&15, row=quad*4+reg
            int grow = tileRow + mrow;
            if (grow < N) tn[(size_t)grow * D + w * 16 + m16] = (__fp16)(c[r] * dts[mrow]);
        }
    }
}

// Final layer: 32-row tile gather -> h in LDS -> MFMA logits -> log_softmax.
__global__ __launch_bounds__(256) void agg_head_mfma(
    const __fp16* __restrict__ t, const int* __restrict__ rowptr,
    const int* __restrict__ col, const float* __restrict__ dinv,
    const float* __restrict__ b, const __fp16* __restrict__ pBc,
    const float* __restrict__ bc, float* __restrict__ out, int N)
{
    __shared__ __align__(16) __fp16 hts[32 * 64];
    __shared__ float lg[32 * 48];
    int w = threadIdx.x >> 6, lane = threadIdx.x & 63;
    int tileRow = blockIdx.x * 32;
    int rowA = tileRow + w * 8;
    int m = lane & 31;
    float a0[8], a1[8];
    gather8_packed(t, rowptr, col, rowA, N, lane, a0, a1);
    float2 bb = ((const float2*)b)[m];
#pragma unroll
    for (int i = 0; i < 8; ++i) {
        int row = rowA + i;
        float h0 = 0.f, h1 = 0.f;
        if (row < N) {
            float dv = dinv[row];
            unsigned pv = *(const unsigned*)&t[((size_t)row << 6) + 2 * m];
            half2_t hp = __builtin_bit_cast(half2_t, pv);
            h0 = fmaxf(fmaf(dv, a0[i] + (float)hp.x, bb.x), 0.f);
            h1 = fmaxf(fmaf(dv, a1[i] + (float)hp.y, bb.y), 0.f);
        }
        if (lane < 32)
            ((unsigned*)hts)[(w * 8 + i) * 32 + m] = pack_f16(h0, h1);
    }
    __syncthreads();
    int quad = lane >> 4, m16 = lane & 15;
    if (w < 3) {
        h8 fb0 = *(const h8*)&pBc[(size_t)(0 * 3 + w) * 512 + lane * 8];
        h8 fb1 = *(const h8*)&pBc[(size_t)(1 * 3 + w) * 512 + lane * 8];
        int n = w * 16 + m16;
        float bcv = (n < NC) ? bc[n] : 0.f;
#pragma unroll
        for (int sub = 0; sub < 2; ++sub) {
            int lr = sub * 16 + m16;
            h8 fa0 = *(const h8*)&hts[lr * 64 + 0 + quad * 8];
            h8 fa1 = *(const h8*)&hts[lr * 64 + 32 + quad * 8];
            f4 c = {0.f, 0.f, 0.f, 0.f};
            c = __builtin_amdgcn_mfma_f32_16x16x32_f16(fa0, fb0, c, 0, 0, 0);
            c = __builtin_amdgcn_mfma_f32_16x16x32_f16(fa1, fb1, c, 0, 0, 0);
#pragma unroll
            for (int r = 0; r < 4; ++r) {
                int mrow = sub * 16 + quad * 4 + r;
                lg[mrow * 48 + n] = (n < NC) ? (c[r] + bcv) : -INFINITY;
            }
        }
    }
    __syncthreads();
#pragma unroll
    for (int sub = 0; sub < 2; ++sub) {
        int row_l = sub * 16 + w * 4 + quad;
        int grow = tileRow + row_l;
        int id = m16;
        float v0 = lg[row_l * 48 + id];
        float v1 = lg[row_l * 48 + id + 16];
        float v2 = lg[row_l * 48 + id + 32];  // -inf for cols >= 40
        float mx = fmaxf(fmaxf(v0, v1), v2);
#pragma unroll
        for (int off = 8; off; off >>= 1) mx = fmaxf(mx, __shfl_xor(mx, off, 64));
        float s = expf(v0 - mx) + expf(v1 - mx) + ((id < 8) ? expf(v2 - mx) : 0.f);
#pragma unroll
        for (int off = 8; off; off >>= 1) s += __shfl_xor(s, off, 64);
        float ls = logf(s);
        if (grow < N) {
            out[(size_t)grow * NC + id] = v0 - mx - ls;
            out[(size_t)grow * NC + id + 16] = v1 - mx - ls;
            if (id < 8) out[(size_t)grow * NC + id + 32] = v2 - mx - ls;
        }
    }
}

extern "C" void kernel_launch(void* const* d_in, const int* in_sizes, int n_in,
                              void* d_out, int out_size, void* d_ws, size_t ws_size,
                              hipStream_t stream) {
    const float* x  = (const float*)d_in[0];
    const int*   ei = (const int*)d_in[1];
    const float* W0 = (const float*)d_in[2];
    const float* b0 = (const float*)d_in[3];
    const float* W1 = (const float*)d_in[4];
    const float* b1 = (const float*)d_in[5];
    const float* W2 = (const float*)d_in[6];
    const float* b2 = (const float*)d_in[7];
    const float* Wc = (const float*)d_in[8];
    const float* bc = (const float*)d_in[9];
    float* out = (float*)d_out;

    const int N = in_sizes[0] / D;   // 100000
    const int E = in_sizes[1] / 2;   // 800000
    const int* src = ei;
    const int* dst = ei + E;

    char* ws = (char*)d_ws;
    float*    dinv    = (float*)(ws + 0);              // N*4
    int*      rowptr  = (int*)  (ws + 524288u);        // (N+1)*4
    int*      cursors = (int*)  (ws + 1048576u);       // NBUCK*4
    int*      col     = (int*)  (ws + 1310720u);       // E*4
    unsigned* staging = (unsigned*)(ws + 5242880u);    // NBUCK*CAP*4
    __fp16*   pB0     = (__fp16*)(ws + 10485760u);     // 8 KB
    __fp16*   pB1     = (__fp16*)(ws + 10493952u);     // 8 KB
    __fp16*   pB2     = (__fp16*)(ws + 10502144u);     // 8 KB
    __fp16*   pBc     = (__fp16*)(ws + 10510336u);     // 6 KB
    __fp16*   A       = (__fp16*)(ws + 16777216u);     // N*64*2
    __fp16*   B       = (__fp16*)(ws + 33554432u);     // N*64*2

    const int BLK = 256;
    const int gT16  = (N + 15) / 16;
    const int gT32  = (N + 31) / 32;
    const int gP1   = (E + CHUNK - 1) / CHUNK;

    pack_weights2<<<16, BLK, 0, stream>>>(W0, W1, W2, Wc, pB0, pB1, pB2, pBc, cursors);
    part1_kernel<<<gP1, BLK, 0, stream>>>(src, dst, E, staging, cursors);
    part2_kernel<<<NBUCK, BLK, 0, stream>>>(staging, cursors, rowptr, dinv, col, N, E);

    transform_mfma<<<gT16, BLK, 0, stream>>>(x, dinv, pB0, A, N);
    fused_layer_mfma<<<gT32, BLK, 0, stream>>>(A, rowptr, col, dinv, b0, pB1, B, N);
    fused_layer_mfma<<<gT32, BLK, 0, stream>>>(B, rowptr, col, dinv, b1, pB2, A, N);
    agg_head_mfma<<<gT32, BLK, 0, stream>>>(A, rowptr, col, dinv, b2, pBc, bc, out, N);
}

// Round 13
// 236.187 us; speedup vs baseline: 1.1177x; 1.1177x over previous
//
#include <hip/hip_runtime.h>
#include <math.h>

#define D 64
#define NC 40

// CSR-build bucket sort parameters (N=100000, E=800000)
#define RPB 512
#define BSHIFT 9
#define NBUCK 200
#define CHUNK 4000
#define CAP 5400

typedef __fp16 half2_t __attribute__((ext_vector_type(2)));
typedef _Float16 h8 __attribute__((ext_vector_type(8)));
typedef float f4 __attribute__((ext_vector_type(4)));

__device__ __forceinline__ unsigned pack_f16(float a, float b) {
    half2_t h = __builtin_amdgcn_cvt_pkrtz(a, b);
    return __builtin_bit_cast(unsigned, h);
}

// Branchless pair-packed gather for 4 rows of one wave, with explicit
// register double-buffering in the common loop (8 loads in flight, no waste).
__device__ __forceinline__ void gather4_packed(
    const __fp16* __restrict__ t, const int* __restrict__ rowptr,
    const int* __restrict__ col, int rowA, int N, int lane,
    float a0[4], float a1[4])
{
    int m = lane & 31;
    bool low = lane < 32;
    int begr[4], degr[4], colv[4], pairs[4];
#pragma unroll
    for (int i = 0; i < 4; ++i) {
        int row = rowA + i;
        int rc = min(row, N - 1);
        int bg = __builtin_amdgcn_readfirstlane(rowptr[rc]);
        int en = __builtin_amdgcn_readfirstlane(rowptr[rc + 1]);
        int dg = (row < N) ? (en - bg) : 0;
        begr[i] = bg; degr[i] = dg;
        int cl = min(dg, 64);
        colv[i] = (lane < cl) ? col[bg + lane] : 0;  // pad -> row 0 (cached)
        pairs[i] = cl >> 1;
        a0[i] = 0.f; a1[i] = 0.f;
    }
    int minp = min(min(pairs[0], pairs[1]), min(pairs[2], pairs[3]));
    int maxp = max(max(pairs[0], pairs[1]), max(pairs[2], pairs[3]));

    // ---- common part, double-buffered: accumulate batch q while batch q+1 flies
    float v0[4], v1[4];
    if (minp > 0) {
#pragma unroll
        for (int i = 0; i < 4; ++i) {
            int ja = __builtin_amdgcn_readlane(colv[i], 0);
            int jb = __builtin_amdgcn_readlane(colv[i], 1);
            int j = low ? ja : jb;
            unsigned pv = *(const unsigned*)&t[((size_t)j << 6) + 2 * m];
            half2_t hp = __builtin_bit_cast(half2_t, pv);
            v0[i] = (float)hp.x; v1[i] = (float)hp.y;
        }
    }
    for (int q = 0; q + 1 < minp; ++q) {
        float w0[4], w1[4];
#pragma unroll
        for (int i = 0; i < 4; ++i) {
            int ja = __builtin_amdgcn_readlane(colv[i], 2 * q + 2);
            int jb = __builtin_amdgcn_readlane(colv[i], 2 * q + 3);
            int j = low ? ja : jb;
            unsigned pv = *(const unsigned*)&t[((size_t)j << 6) + 2 * m];
            half2_t hp = __builtin_bit_cast(half2_t, pv);
            w0[i] = (float)hp.x; w1[i] = (float)hp.y;
        }
#pragma unroll
        for (int i = 0; i < 4; ++i) {
            a0[i] += v0[i]; a1[i] += v1[i];
            v0[i] = w0[i]; v1[i] = w1[i];
        }
    }
    if (minp > 0) {
#pragma unroll
        for (int i = 0; i < 4; ++i) { a0[i] += v0[i]; a1[i] += v1[i]; }
    }

    // ---- masked remainder
    for (int q = minp; q < maxp; ++q) {
        float u0[4], u1[4], mk[4];
#pragma unroll
        for (int i = 0; i < 4; ++i) {
            int ja = __builtin_amdgcn_readlane(colv[i], 2 * q);
            int jb = __builtin_amdgcn_readlane(colv[i], 2 * q + 1);
            int j = low ? ja : jb;
            unsigned pv = *(const unsigned*)&t[((size_t)j << 6) + 2 * m];
            half2_t hp = __builtin_bit_cast(half2_t, pv);
            u0[i] = (float)hp.x; u1[i] = (float)hp.y;
            mk[i] = (q < pairs[i]) ? 1.f : 0.f;
        }
#pragma unroll
        for (int i = 0; i < 4; ++i) {
            a0[i] = fmaf(mk[i], u0[i], a0[i]);
            a1[i] = fmaf(mk[i], u1[i], a1[i]);
        }
    }
#pragma unroll
    for (int i = 0; i < 4; ++i) {
        int cl = min(degr[i], 64);
        if (cl & 1) {                              // uniform branch, odd tail
            int j = __builtin_amdgcn_readlane(colv[i], cl - 1);
            unsigned pv = *(const unsigned*)&t[((size_t)j << 6) + 2 * m];
            half2_t hp = __builtin_bit_cast(half2_t, pv);
            float mk2 = low ? 1.f : 0.f;           // count once
            a0[i] = fmaf(mk2, (float)hp.x, a0[i]);
            a1[i] = fmaf(mk2, (float)hp.y, a1[i]);
        }
        for (int p = begr[i] + 64; p < begr[i] + degr[i]; ++p) {  // deg>64
            int j = __builtin_amdgcn_readfirstlane(col[p]);
            unsigned pv = *(const unsigned*)&t[((size_t)j << 6) + 2 * m];
            half2_t hp = __builtin_bit_cast(half2_t, pv);
            float mk2 = low ? 1.f : 0.f;
            a0[i] = fmaf(mk2, (float)hp.x, a0[i]);
            a1[i] = fmaf(mk2, (float)hp.y, a1[i]);
        }
    }
#pragma unroll
    for (int i = 0; i < 4; ++i) {                  // combine halves
        a0[i] += __shfl_xor(a0[i], 32, 64);
        a1[i] += __shfl_xor(a1[i], 32, 64);
    }
}

// ---- CSR build: two-pass LDS-staged bucket sort ------------------------

__global__ __launch_bounds__(256) void part1_kernel(
    const int* __restrict__ src, const int* __restrict__ dst, int E,
    unsigned* __restrict__ staging, int* __restrict__ cursors)
{
    __shared__ int hist[NBUCK], off[NBUCK], cnt2[NBUCK], rbase[NBUCK];
    __shared__ int tmp[256];
    __shared__ unsigned packed[CHUNK];
    __shared__ unsigned char bof[CHUNK];
    int tid = threadIdx.x;
    int beg = blockIdx.x * CHUNK;
    int n = min(CHUNK, E - beg);
    for (int i = tid; i < NBUCK; i += 256) { hist[i] = 0; cnt2[i] = 0; }
    __syncthreads();
    for (int i = tid; i < n; i += 256) {
        int d = dst[beg + i];
        atomicAdd(&hist[d >> BSHIFT], 1);
    }
    __syncthreads();
    int v = (tid < NBUCK) ? hist[tid] : 0;
    tmp[tid] = v;
    __syncthreads();
    for (int o = 1; o < 256; o <<= 1) {
        int t = (tid >= o) ? tmp[tid - o] : 0;
        __syncthreads();
        tmp[tid] += t;
        __syncthreads();
    }
    if (tid < NBUCK) {
        off[tid] = tmp[tid] - v;
        rbase[tid] = v ? atomicAdd(&cursors[tid], v) : 0;
    }
    __syncthreads();
    for (int i = tid; i < n; i += 256) {
        int d = dst[beg + i];
        int s = src[beg + i];
        int b = d >> BSHIFT;
        int p = off[b] + atomicAdd(&cnt2[b], 1);
        packed[p] = ((unsigned)(d & (RPB - 1)) << 17) | (unsigned)s;
        bof[p] = (unsigned char)b;
    }
    __syncthreads();
    for (int i = tid; i < n; i += 256) {
        int b = bof[i];
        int idx = rbase[b] + (i - off[b]);
        if (idx < CAP) staging[(size_t)b * CAP + idx] = packed[i];
    }
}

__global__ __launch_bounds__(256) void part2_kernel(
    const unsigned* __restrict__ staging, const int* __restrict__ cursors,
    int* __restrict__ rowptr, float* __restrict__ dinv, int* __restrict__ col,
    int N, int E)
{
    __shared__ int hist[RPB], off[RPB], cur[RPB];
    __shared__ int tmp[256];
    __shared__ int colstage[CAP];
    __shared__ int sb[2];
    int tid = threadIdx.x;
    int b = blockIdx.x;
    int v = (tid < NBUCK) ? cursors[tid] : 0;
    tmp[tid] = v;
    __syncthreads();
    for (int o = 1; o < 256; o <<= 1) {
        int t = (tid >= o) ? tmp[tid - o] : 0;
        __syncthreads();
        tmp[tid] += t;
        __syncthreads();
    }
    if (tid == 0) { sb[0] = (b ? tmp[b - 1] : 0); sb[1] = min(cursors[b], CAP); }
    for (int i = tid; i < RPB; i += 256) { hist[i] = 0; cur[i] = 0; }
    __syncthreads();
    int base = sb[0], nE = sb[1];
    const unsigned* stg = staging + (size_t)b * CAP;
    for (int i = tid; i < nE; i += 256) atomicAdd(&hist[stg[i] >> 17], 1);
    __syncthreads();
    int a0 = hist[2 * tid], a1 = hist[2 * tid + 1];
    int ps = a0 + a1;
    tmp[tid] = ps;
    __syncthreads();
    for (int o = 1; o < 256; o <<= 1) {
        int t = (tid >= o) ? tmp[tid - o] : 0;
        __syncthreads();
        tmp[tid] += t;
        __syncthreads();
    }
    int pex = tmp[tid] - ps;
    off[2 * tid] = pex;
    off[2 * tid + 1] = pex + a0;
    __syncthreads();
    int r0 = b * RPB;
    for (int r = tid; r < RPB; r += 256) {
        int row = r0 + r;
        if (row < N) {
            rowptr[row] = base + off[r];
            dinv[row] = rsqrtf((float)hist[r] + 1.0f);  // +1 self-loop
        }
    }
    if (b == NBUCK - 1 && tid == 0) rowptr[N] = E;
    for (int i = tid; i < nE; i += 256) {
        unsigned pv = stg[i];
        int row = pv >> 17;
        int p = off[row] + atomicAdd(&cur[row], 1);
        colstage[p] = (int)(pv & 0x1FFFFu);
    }
    __syncthreads();
    for (int i = tid; i < nE; i += 256) col[base + i] = colstage[i];
}

// ---- Weight packing (also zeroes cursors) -------------------------------
__global__ void pack_weights2(const float* __restrict__ W0, const float* __restrict__ W1,
                              const float* __restrict__ W2, const float* __restrict__ Wc,
                              __fp16* __restrict__ pB0, __fp16* __restrict__ pB1,
                              __fp16* __restrict__ pB2, __fp16* __restrict__ pBc,
                              int* __restrict__ cursors) {
    int i = blockIdx.x * blockDim.x + threadIdx.x;
    if (i < NBUCK) cursors[i] = 0;
    if (i < 4096) {
        int j = i & 7, lane = (i >> 3) & 63, st = i >> 9;  // st = s*4+t
        int s = st >> 2, t = st & 3;
        int k = 32 * s + ((lane >> 4) * 8 + j);
        int n = 16 * t + (lane & 15);
        pB0[i] = (__fp16)W0[k * D + n];
        pB1[i] = (__fp16)W1[k * D + n];
        pB2[i] = (__fp16)W2[k * D + n];
    }
    if (i < 3072) {
        int j = i & 7, lane = (i >> 3) & 63, st = i >> 9;  // st = s*3+t
        int s = st / 3, t = st % 3;
        int k = 32 * s + ((lane >> 4) * 8 + j);
        int n = 16 * t + (lane & 15);
        pBc[i] = (n < NC) ? (__fp16)Wc[k * NC + n] : (__fp16)0.f;
    }
}

// ---- Compute -----------------------------------------------------------

// t = dinv * (x @ W0) via MFMA with LDS-staged A (coalesced x loads).
__global__ __launch_bounds__(256) void transform_mfma(
    const float* __restrict__ x, const float* __restrict__ dinv,
    const __fp16* __restrict__ pB0, __fp16* __restrict__ t, int N)
{
    __shared__ __align__(16) __fp16 hts[16 * 64];
    int w = threadIdx.x >> 6, lane = threadIdx.x & 63;
    int tileRow = blockIdx.x * 16;
#pragma unroll
    for (int i = 0; i < 4; ++i) {
        int row = tileRow + w * 4 + i;
        float v = (row < N) ? x[(size_t)row * D + lane] : 0.f;  // coalesced
        hts[(w * 4 + i) * 64 + lane] = (__fp16)v;
    }
    __syncthreads();
    int quad = lane >> 4, m16 = lane & 15;
    h8 fa0 = *(const h8*)&hts[m16 * 64 + 0 + quad * 8];   // A[m][k], k=quad*8+j
    h8 fa1 = *(const h8*)&hts[m16 * 64 + 32 + quad * 8];
    h8 fb0 = *(const h8*)&pB0[(size_t)(0 * 4 + w) * 512 + lane * 8];
    h8 fb1 = *(const h8*)&pB0[(size_t)(1 * 4 + w) * 512 + lane * 8];
    f4 c = {0.f, 0.f, 0.f, 0.f};
    c = __builtin_amdgcn_mfma_f32_16x16x32_f16(fa0, fb0, c, 0, 0, 0);
    c = __builtin_amdgcn_mfma_f32_16x16x32_f16(fa1, fb1, c, 0, 0, 0);
#pragma unroll
    for (int r = 0; r < 4; ++r) {
        int mrow = quad * 4 + r;           // C/D: col=lane&15, row=quad*4+reg
        int grow = tileRow + mrow;
        if (grow < N) t[(size_t)grow * D + w * 16 + m16] = (__fp16)(c[r] * dinv[grow]);
    }
}

// Block = 4 waves = 16-row tile. Pair-packed gather -> LDS -> MFMA h@W.
__global__ __launch_bounds__(256) void fused_layer_mfma(
    const __fp16* __restrict__ t, const int* __restrict__ rowptr,
    const int* __restrict__ col, const float* __restrict__ dinv,
    const float* __restrict__ b, const __fp16* __restrict__ pB,
    __fp16* __restrict__ tn, int N)
{
    __shared__ __align__(16) __fp16 hts[16 * 64];
    __shared__ float dts[16];
    int w = threadIdx.x >> 6, lane = threadIdx.x & 63;
    int tileRow = blockIdx.x * 16;
    int rowA = tileRow + w * 4;
    int m = lane & 31;
    float a0[4], a1[4];
    gather4_packed(t, rowptr, col, rowA, N, lane, a0, a1);
    float2 bb = ((const float2*)b)[m];
#pragma unroll
    for (int i = 0; i < 4; ++i) {
        int row = rowA + i;
        float h0 = 0.f, h1 = 0.f, dv = 0.f;
        if (row < N) {                         // uniform
            dv = dinv[row];
            unsigned pv = *(const unsigned*)&t[((size_t)row << 6) + 2 * m];
            half2_t hp = __builtin_bit_cast(half2_t, pv);   // self-loop
            h0 = fmaxf(fmaf(dv, a0[i] + (float)hp.x, bb.x), 0.f);
            h1 = fmaxf(fmaf(dv, a1[i] + (float)hp.y, bb.y), 0.f);
        }
        if (lane < 32) {
            ((unsigned*)hts)[(w * 4 + i) * 32 + m] = pack_f16(h0, h1);
            if (lane == 0) dts[w * 4 + i] = dv;
        }
    }
    __syncthreads();
    int quad = lane >> 4, m16 = lane & 15;
    h8 fa0 = *(const h8*)&hts[m16 * 64 + 0 + quad * 8];   // A[m][k], k=quad*8+j
    h8 fa1 = *(const h8*)&hts[m16 * 64 + 32 + quad * 8];
    h8 fb0 = *(const h8*)&pB[(size_t)(0 * 4 + w) * 512 + lane * 8];
    h8 fb1 = *(const h8*)&pB[(size_t)(1 * 4 + w) * 512 + lane * 8];
    f4 c = {0.f, 0.f, 0.f, 0.f};
    c = __builtin_amdgcn_mfma_f32_16x16x32_f16(fa0, fb0, c, 0, 0, 0);
    c = __builtin_amdgcn_mfma_f32_16x16x32_f16(fa1, fb1, c, 0, 0, 0);
#pragma unroll
    for (int r = 0; r < 4; ++r) {
        int mrow = quad * 4 + r;           // C/D: col=lane&15, row=quad*4+reg
        int grow = tileRow + mrow;
        if (grow < N) tn[(size_t)grow * D + w * 16 + m16] = (__fp16)(c[r] * dts[mrow]);
    }
}

// Final layer: pair-packed gather -> h in LDS -> MFMA logits -> log_softmax.
__global__ __launch_bounds__(256) void agg_head_mfma(
    const __fp16* __restrict__ t, const int* __restrict__ rowptr,
    const int* __restrict__ col, const float* __restrict__ dinv,
    const float* __restrict__ b, const __fp16* __restrict__ pBc,
    const float* __restrict__ bc, float* __restrict__ out, int N)
{
    __shared__ __align__(16) __fp16 hts[16 * 64];
    __shared__ float lg[16 * 48];
    int w = threadIdx.x >> 6, lane = threadIdx.x & 63;
    int tileRow = blockIdx.x * 16;
    int rowA = tileRow + w * 4;
    int m = lane & 31;
    float a0[4], a1[4];
    gather4_packed(t, rowptr, col, rowA, N, lane, a0, a1);
    float2 bb = ((const float2*)b)[m];
#pragma unroll
    for (int i = 0; i < 4; ++i) {
        int row = rowA + i;
        float h0 = 0.f, h1 = 0.f;
        if (row < N) {
            float dv = dinv[row];
            unsigned pv = *(const unsigned*)&t[((size_t)row << 6) + 2 * m];
            half2_t hp = __builtin_bit_cast(half2_t, pv);
            h0 = fmaxf(fmaf(dv, a0[i] + (float)hp.x, bb.x), 0.f);
            h1 = fmaxf(fmaf(dv, a1[i] + (float)hp.y, bb.y), 0.f);
        }
        if (lane < 32)
            ((unsigned*)hts)[(w * 4 + i) * 32 + m] = pack_f16(h0, h1);
    }
    __syncthreads();
    int quad = lane >> 4, m16 = lane & 15;
    if (w < 3) {
        h8 fa0 = *(const h8*)&hts[m16 * 64 + 0 + quad * 8];
        h8 fa1 = *(const h8*)&hts[m16 * 64 + 32 + quad * 8];
        h8 fb0 = *(const h8*)&pBc[(size_t)(0 * 3 + w) * 512 + lane * 8];
        h8 fb1 = *(const h8*)&pBc[(size_t)(1 * 3 + w) * 512 + lane * 8];
        f4 c = {0.f, 0.f, 0.f, 0.f};
        c = __builtin_amdgcn_mfma_f32_16x16x32_f16(fa0, fb0, c, 0, 0, 0);
        c = __builtin_amdgcn_mfma_f32_16x16x32_f16(fa1, fb1, c, 0, 0, 0);
        int n = w * 16 + m16;
        float bcv = (n < NC) ? bc[n] : 0.f;
#pragma unroll
        for (int r = 0; r < 4; ++r) {
            int mrow = quad * 4 + r;
            lg[mrow * 48 + n] = (n < NC) ? (c[r] + bcv) : -INFINITY;
        }
    }
    __syncthreads();
    int row_l = w * 4 + quad;
    int grow = tileRow + row_l;
    int id = m16;
    float v0 = lg[row_l * 48 + id];
    float v1 = lg[row_l * 48 + id + 16];
    float v2 = lg[row_l * 48 + id + 32];  // -inf for cols >= 40
    float mx = fmaxf(fmaxf(v0, v1), v2);
#pragma unroll
    for (int off = 8; off; off >>= 1) mx = fmaxf(mx, __shfl_xor(mx, off, 64));
    float s = expf(v0 - mx) + expf(v1 - mx) + ((id < 8) ? expf(v2 - mx) : 0.f);
#pragma unroll
    for (int off = 8; off; off >>= 1) s += __shfl_xor(s, off, 64);
    float ls = logf(s);
    if (grow < N) {
        out[(size_t)grow * NC + id] = v0 - mx - ls;
        out[(size_t)grow * NC + id + 16] = v1 - mx - ls;
        if (id < 8) out[(size_t)grow * NC + id + 32] = v2 - mx - ls;
    }
}

extern "C" void kernel_launch(void* const* d_in, const int* in_sizes, int n_in,
                              void* d_out, int out_size, void* d_ws, size_t ws_size,
                              hipStream_t stream) {
    const float* x  = (const float*)d_in[0];
    const int*   ei = (const int*)d_in[1];
    const float* W0 = (const float*)d_in[2];
    const float* b0 = (const float*)d_in[3];
    const float* W1 = (const float*)d_in[4];
    const float* b1 = (const float*)d_in[5];
    const float* W2 = (const float*)d_in[6];
    const float* b2 = (const float*)d_in[7];
    const float* Wc = (const float*)d_in[8];
    const float* bc = (const float*)d_in[9];
    float* out = (float*)d_out;

    const int N = in_sizes[0] / D;   // 100000
    const int E = in_sizes[1] / 2;   // 800000
    const int* src = ei;
    const int* dst = ei + E;

    char* ws = (char*)d_ws;
    float*    dinv    = (float*)(ws + 0);              // N*4
    int*      rowptr  = (int*)  (ws + 524288u);        // (N+1)*4
    int*      cursors = (int*)  (ws + 1048576u);       // NBUCK*4
    int*      col     = (int*)  (ws + 1310720u);       // E*4
    unsigned* staging = (unsigned*)(ws + 5242880u);    // NBUCK*CAP*4
    __fp16*   pB0     = (__fp16*)(ws + 10485760u);     // 8 KB
    __fp16*   pB1     = (__fp16*)(ws + 10493952u);     // 8 KB
    __fp16*   pB2     = (__fp16*)(ws + 10502144u);     // 8 KB
    __fp16*   pBc     = (__fp16*)(ws + 10510336u);     // 6 KB
    __fp16*   A       = (__fp16*)(ws + 16777216u);     // N*64*2
    __fp16*   B       = (__fp16*)(ws + 33554432u);     // N*64*2

    const int BLK = 256;
    const int gT16  = (N + 15) / 16;
    const int gP1   = (E + CHUNK - 1) / CHUNK;

    pack_weights2<<<16, BLK, 0, stream>>>(W0, W1, W2, Wc, pB0, pB1, pB2, pBc, cursors);
    part1_kernel<<<gP1, BLK, 0, stream>>>(src, dst, E, staging, cursors);
    part2_kernel<<<NBUCK, BLK, 0, stream>>>(staging, cursors, rowptr, dinv, col, N, E);

    transform_mfma<<<gT16, BLK, 0, stream>>>(x, dinv, pB0, A, N);
    fused_layer_mfma<<<gT16, BLK, 0, stream>>>(A, rowptr, col, dinv, b0, pB1, B, N);
    fused_layer_mfma<<<gT16, BLK, 0, stream>>>(B, rowptr, col, dinv, b1, pB2, A, N);
    agg_head_mfma<<<gT16, BLK, 0, stream>>>(A, rowptr, col, dinv, b2, pBc, bc, out, N);
}

// Round 14
// 227.855 us; speedup vs baseline: 1.1585x; 1.0366x over previous
//
#include <hip/hip_runtime.h>
#include <math.h>

#define D 64
#define NC 40

// CSR-build bucket sort parameters (N=100000, E=800000)
#define RPB 512
#define BSHIFT 9
#define NBUCK 200
#define CHUNK 4000
#define CAP 5400

typedef __fp16 half2_t __attribute__((ext_vector_type(2)));
typedef _Float16 h8 __attribute__((ext_vector_type(8)));
typedef float f4 __attribute__((ext_vector_type(4)));
typedef float f2 __attribute__((ext_vector_type(2)));

__device__ __forceinline__ unsigned pack_f16(float a, float b) {
    half2_t h = __builtin_amdgcn_cvt_pkrtz(a, b);
    return __builtin_bit_cast(unsigned, h);
}

// fp8 e4m3 (HW) helpers: t buffer is fp8, accumulate in f32.
__device__ __forceinline__ f2 unpack_fp8(unsigned short v) {
    return __builtin_amdgcn_cvt_pk_f32_fp8((int)(unsigned)v, false);
}
__device__ __forceinline__ unsigned char to_fp8(float v) {
    return (unsigned char)(__builtin_amdgcn_cvt_pk_fp8_f32(v, v, 0, false) & 0xFF);
}

// Branchless pair-packed gather for 4 rows of one wave over fp8 t.
// Lane l accumulates dims (2*(l&31), 2*(l&31)+1); low half even neighbors,
// high half odd; halves combined at the end.
__device__ __forceinline__ void gather4_packed(
    const unsigned char* __restrict__ t8, const int* __restrict__ rowptr,
    const int* __restrict__ col, int rowA, int N, int lane,
    float a0[4], float a1[4])
{
    int m = lane & 31;
    bool low = lane < 32;
    int begr[4], degr[4], colv[4], pairs[4];
#pragma unroll
    for (int i = 0; i < 4; ++i) {
        int row = rowA + i;
        int rc = min(row, N - 1);
        int bg = __builtin_amdgcn_readfirstlane(rowptr[rc]);
        int en = __builtin_amdgcn_readfirstlane(rowptr[rc + 1]);
        int dg = (row < N) ? (en - bg) : 0;
        begr[i] = bg; degr[i] = dg;
        int cl = min(dg, 64);
        colv[i] = (lane < cl) ? col[bg + lane] : 0;  // pad -> row 0 (cached)
        pairs[i] = cl >> 1;
        a0[i] = 0.f; a1[i] = 0.f;
    }
    int minp = min(min(pairs[0], pairs[1]), min(pairs[2], pairs[3]));
    int maxp = max(max(pairs[0], pairs[1]), max(pairs[2], pairs[3]));
    int q = 0;
#pragma unroll 2
    for (; q < minp; ++q) {                        // unmasked common part
        unsigned short pv[4];
#pragma unroll
        for (int i = 0; i < 4; ++i) {
            int ja = __builtin_amdgcn_readlane(colv[i], 2 * q);
            int jb = __builtin_amdgcn_readlane(colv[i], 2 * q + 1);
            int j = low ? ja : jb;
            pv[i] = *(const unsigned short*)&t8[((size_t)j << 6) + 2 * m];
        }
#pragma unroll
        for (int i = 0; i < 4; ++i) {
            f2 hp = unpack_fp8(pv[i]);
            a0[i] += hp.x; a1[i] += hp.y;
        }
    }
    for (; q < maxp; ++q) {                        // masked remainder
        unsigned short pv[4]; float mk[4];
#pragma unroll
        for (int i = 0; i < 4; ++i) {
            int ja = __builtin_amdgcn_readlane(colv[i], 2 * q);
            int jb = __builtin_amdgcn_readlane(colv[i], 2 * q + 1);
            int j = low ? ja : jb;
            pv[i] = *(const unsigned short*)&t8[((size_t)j << 6) + 2 * m];
            mk[i] = (q < pairs[i]) ? 1.f : 0.f;
        }
#pragma unroll
        for (int i = 0; i < 4; ++i) {
            f2 hp = unpack_fp8(pv[i]);
            a0[i] = fmaf(mk[i], hp.x, a0[i]);
            a1[i] = fmaf(mk[i], hp.y, a1[i]);
        }
    }
#pragma unroll
    for (int i = 0; i < 4; ++i) {
        int cl = min(degr[i], 64);
        if (cl & 1) {                              // uniform branch, odd tail
            int j = __builtin_amdgcn_readlane(colv[i], cl - 1);
            f2 hp = unpack_fp8(*(const unsigned short*)&t8[((size_t)j << 6) + 2 * m]);
            float mk2 = low ? 1.f : 0.f;           // count once
            a0[i] = fmaf(mk2, hp.x, a0[i]);
            a1[i] = fmaf(mk2, hp.y, a1[i]);
        }
        for (int p = begr[i] + 64; p < begr[i] + degr[i]; ++p) {  // deg>64
            int j = __builtin_amdgcn_readfirstlane(col[p]);
            f2 hp = unpack_fp8(*(const unsigned short*)&t8[((size_t)j << 6) + 2 * m]);
            float mk2 = low ? 1.f : 0.f;
            a0[i] = fmaf(mk2, hp.x, a0[i]);
            a1[i] = fmaf(mk2, hp.y, a1[i]);
        }
    }
#pragma unroll
    for (int i = 0; i < 4; ++i) {                  // combine halves
        a0[i] += __shfl_xor(a0[i], 32, 64);
        a1[i] += __shfl_xor(a1[i], 32, 64);
    }
}

// ---- CSR build: two-pass LDS-staged bucket sort ------------------------

__global__ __launch_bounds__(256) void part1_kernel(
    const int* __restrict__ src, const int* __restrict__ dst, int E,
    unsigned* __restrict__ staging, int* __restrict__ cursors)
{
    __shared__ int hist[NBUCK], off[NBUCK], cnt2[NBUCK], rbase[NBUCK];
    __shared__ int tmp[256];
    __shared__ unsigned packed[CHUNK];
    __shared__ unsigned char bof[CHUNK];
    int tid = threadIdx.x;
    int beg = blockIdx.x * CHUNK;
    int n = min(CHUNK, E - beg);
    for (int i = tid; i < NBUCK; i += 256) { hist[i] = 0; cnt2[i] = 0; }
    __syncthreads();
    for (int i = tid; i < n; i += 256) {
        int d = dst[beg + i];
        atomicAdd(&hist[d >> BSHIFT], 1);
    }
    __syncthreads();
    int v = (tid < NBUCK) ? hist[tid] : 0;
    tmp[tid] = v;
    __syncthreads();
    for (int o = 1; o < 256; o <<= 1) {
        int t = (tid >= o) ? tmp[tid - o] : 0;
        __syncthreads();
        tmp[tid] += t;
        __syncthreads();
    }
    if (tid < NBUCK) {
        off[tid] = tmp[tid] - v;
        rbase[tid] = v ? atomicAdd(&cursors[tid], v) : 0;
    }
    __syncthreads();
    for (int i = tid; i < n; i += 256) {
        int d = dst[beg + i];
        int s = src[beg + i];
        int b = d >> BSHIFT;
        int p = off[b] + atomicAdd(&cnt2[b], 1);
        packed[p] = ((unsigned)(d & (RPB - 1)) << 17) | (unsigned)s;
        bof[p] = (unsigned char)b;
    }
    __syncthreads();
    for (int i = tid; i < n; i += 256) {
        int b = bof[i];
        int idx = rbase[b] + (i - off[b]);
        if (idx < CAP) staging[(size_t)b * CAP + idx] = packed[i];
    }
}

__global__ __launch_bounds__(256) void part2_kernel(
    const unsigned* __restrict__ staging, const int* __restrict__ cursors,
    int* __restrict__ rowptr, float* __restrict__ dinv, int* __restrict__ col,
    int N, int E)
{
    __shared__ int hist[RPB], off[RPB], cur[RPB];
    __shared__ int tmp[256];
    __shared__ int colstage[CAP];
    __shared__ int sb[2];
    int tid = threadIdx.x;
    int b = blockIdx.x;
    int v = (tid < NBUCK) ? cursors[tid] : 0;
    tmp[tid] = v;
    __syncthreads();
    for (int o = 1; o < 256; o <<= 1) {
        int t = (tid >= o) ? tmp[tid - o] : 0;
        __syncthreads();
        tmp[tid] += t;
        __syncthreads();
    }
    if (tid == 0) { sb[0] = (b ? tmp[b - 1] : 0); sb[1] = min(cursors[b], CAP); }
    for (int i = tid; i < RPB; i += 256) { hist[i] = 0; cur[i] = 0; }
    __syncthreads();
    int base = sb[0], nE = sb[1];
    const unsigned* stg = staging + (size_t)b * CAP;
    for (int i = tid; i < nE; i += 256) atomicAdd(&hist[stg[i] >> 17], 1);
    __syncthreads();
    int a0 = hist[2 * tid], a1 = hist[2 * tid + 1];
    int ps = a0 + a1;
    tmp[tid] = ps;
    __syncthreads();
    for (int o = 1; o < 256; o <<= 1) {
        int t = (tid >= o) ? tmp[tid - o] : 0;
        __syncthreads();
        tmp[tid] += t;
        __syncthreads();
    }
    int pex = tmp[tid] - ps;
    off[2 * tid] = pex;
    off[2 * tid + 1] = pex + a0;
    __syncthreads();
    int r0 = b * RPB;
    for (int r = tid; r < RPB; r += 256) {
        int row = r0 + r;
        if (row < N) {
            rowptr[row] = base + off[r];
            dinv[row] = rsqrtf((float)hist[r] + 1.0f);  // +1 self-loop
        }
    }
    if (b == NBUCK - 1 && tid == 0) rowptr[N] = E;
    for (int i = tid; i < nE; i += 256) {
        unsigned pv = stg[i];
        int row = pv >> 17;
        int p = off[row] + atomicAdd(&cur[row], 1);
        colstage[p] = (int)(pv & 0x1FFFFu);
    }
    __syncthreads();
    for (int i = tid; i < nE; i += 256) col[base + i] = colstage[i];
}

// ---- Weight packing (also zeroes cursors) -------------------------------
__global__ void pack_weights2(const float* __restrict__ W0, const float* __restrict__ W1,
                              const float* __restrict__ W2, const float* __restrict__ Wc,
                              __fp16* __restrict__ pB0, __fp16* __restrict__ pB1,
                              __fp16* __restrict__ pB2, __fp16* __restrict__ pBc,
                              int* __restrict__ cursors) {
    int i = blockIdx.x * blockDim.x + threadIdx.x;
    if (i < NBUCK) cursors[i] = 0;
    if (i < 4096) {
        int j = i & 7, lane = (i >> 3) & 63, st = i >> 9;  // st = s*4+t
        int s = st >> 2, t = st & 3;
        int k = 32 * s + ((lane >> 4) * 8 + j);
        int n = 16 * t + (lane & 15);
        pB0[i] = (__fp16)W0[k * D + n];
        pB1[i] = (__fp16)W1[k * D + n];
        pB2[i] = (__fp16)W2[k * D + n];
    }
    if (i < 3072) {
        int j = i & 7, lane = (i >> 3) & 63, st = i >> 9;  // st = s*3+t
        int s = st / 3, t = st % 3;
        int k = 32 * s + ((lane >> 4) * 8 + j);
        int n = 16 * t + (lane & 15);
        pBc[i] = (n < NC) ? (__fp16)Wc[k * NC + n] : (__fp16)0.f;
    }
}

// ---- Compute -----------------------------------------------------------

// t (fp8) = dinv * (x @ W0) via MFMA with LDS-staged A (coalesced x loads).
__global__ __launch_bounds__(256) void transform_mfma(
    const float* __restrict__ x, const float* __restrict__ dinv,
    const __fp16* __restrict__ pB0, unsigned char* __restrict__ t8, int N)
{
    __shared__ __align__(16) __fp16 hts[16 * 64];
    int w = threadIdx.x >> 6, lane = threadIdx.x & 63;
    int tileRow = blockIdx.x * 16;
#pragma unroll
    for (int i = 0; i < 4; ++i) {
        int row = tileRow + w * 4 + i;
        float v = (row < N) ? x[(size_t)row * D + lane] : 0.f;  // coalesced
        hts[(w * 4 + i) * 64 + lane] = (__fp16)v;
    }
    __syncthreads();
    int quad = lane >> 4, m16 = lane & 15;
    h8 fa0 = *(const h8*)&hts[m16 * 64 + 0 + quad * 8];   // A[m][k], k=quad*8+j
    h8 fa1 = *(const h8*)&hts[m16 * 64 + 32 + quad * 8];
    h8 fb0 = *(const h8*)&pB0[(size_t)(0 * 4 + w) * 512 + lane * 8];
    h8 fb1 = *(const h8*)&pB0[(size_t)(1 * 4 + w) * 512 + lane * 8];
    f4 c = {0.f, 0.f, 0.f, 0.f};
    c = __builtin_amdgcn_mfma_f32_16x16x32_f16(fa0, fb0, c, 0, 0, 0);
    c = __builtin_amdgcn_mfma_f32_16x16x32_f16(fa1, fb1, c, 0, 0, 0);
#pragma unroll
    for (int r = 0; r < 4; ++r) {
        int mrow = quad * 4 + r;           // C/D: col=lane&15, row=quad*4+reg
        int grow = tileRow + mrow;
        if (grow < N) t8[(size_t)grow * D + w * 16 + m16] = to_fp8(c[r] * dinv[grow]);
    }
}

// Block = 4 waves = 16-row tile. fp8 gather -> h in LDS (f16) -> MFMA h@W -> fp8 t.
__global__ __launch_bounds__(256) void fused_layer_mfma(
    const unsigned char* __restrict__ t8, const int* __restrict__ rowptr,
    const int* __restrict__ col, const float* __restrict__ dinv,
    const float* __restrict__ b, const __fp16* __restrict__ pB,
    unsigned char* __restrict__ tn8, int N)
{
    __shared__ __align__(16) __fp16 hts[16 * 64];
    __shared__ float dts[16];
    int w = threadIdx.x >> 6, lane = threadIdx.x & 63;
    int tileRow = blockIdx.x * 16;
    int rowA = tileRow + w * 4;
    int m = lane & 31;
    float a0[4], a1[4];
    gather4_packed(t8, rowptr, col, rowA, N, lane, a0, a1);
    float2 bb = ((const float2*)b)[m];
#pragma unroll
    for (int i = 0; i < 4; ++i) {
        int row = rowA + i;
        float h0 = 0.f, h1 = 0.f, dv = 0.f;
        if (row < N) {                         // uniform
            dv = dinv[row];
            f2 hp = unpack_fp8(*(const unsigned short*)&t8[((size_t)row << 6) + 2 * m]);
            h0 = fmaxf(fmaf(dv, a0[i] + hp.x, bb.x), 0.f);
            h1 = fmaxf(fmaf(dv, a1[i] + hp.y, bb.y), 0.f);
        }
        if (lane < 32) {
            ((unsigned*)hts)[(w * 4 + i) * 32 + m] = pack_f16(h0, h1);
            if (lane == 0) dts[w * 4 + i] = dv;
        }
    }
    __syncthreads();
    int quad = lane >> 4, m16 = lane & 15;
    h8 fa0 = *(const h8*)&hts[m16 * 64 + 0 + quad * 8];   // A[m][k], k=quad*8+j
    h8 fa1 = *(const h8*)&hts[m16 * 64 + 32 + quad * 8];
    h8 fb0 = *(const h8*)&pB[(size_t)(0 * 4 + w) * 512 + lane * 8];
    h8 fb1 = *(const h8*)&pB[(size_t)(1 * 4 + w) * 512 + lane * 8];
    f4 c = {0.f, 0.f, 0.f, 0.f};
    c = __builtin_amdgcn_mfma_f32_16x16x32_f16(fa0, fb0, c, 0, 0, 0);
    c = __builtin_amdgcn_mfma_f32_16x16x32_f16(fa1, fb1, c, 0, 0, 0);
#pragma unroll
    for (int r = 0; r < 4; ++r) {
        int mrow = quad * 4 + r;           // C/D: col=lane&15, row=quad*4+reg
        int grow = tileRow + mrow;
        if (grow < N) tn8[(size_t)grow * D + w * 16 + m16] = to_fp8(c[r] * dts[mrow]);
    }
}

// Final layer: fp8 gather -> h in LDS -> MFMA logits -> log_softmax.
__global__ __launch_bounds__(256) void agg_head_mfma(
    const unsigned char* __restrict__ t8, const int* __restrict__ rowptr,
    const int* __restrict__ col, const float* __restrict__ dinv,
    const float* __restrict__ b, const __fp16* __restrict__ pBc,
    const float* __restrict__ bc, float* __restrict__ out, int N)
{
    __shared__ __align__(16) __fp16 hts[16 * 64];
    __shared__ float lg[16 * 48];
    int w = threadIdx.x >> 6, lane = threadIdx.x & 63;
    int tileRow = blockIdx.x * 16;
    int rowA = tileRow + w * 4;
    int m = lane & 31;
    float a0[4], a1[4];
    gather4_packed(t8, rowptr, col, rowA, N, lane, a0, a1);
    float2 bb = ((const float2*)b)[m];
#pragma unroll
    for (int i = 0; i < 4; ++i) {
        int row = rowA + i;
        float h0 = 0.f, h1 = 0.f;
        if (row < N) {
            float dv = dinv[row];
            f2 hp = unpack_fp8(*(const unsigned short*)&t8[((size_t)row << 6) + 2 * m]);
            h0 = fmaxf(fmaf(dv, a0[i] + hp.x, bb.x), 0.f);
            h1 = fmaxf(fmaf(dv, a1[i] + hp.y, bb.y), 0.f);
        }
        if (lane < 32)
            ((unsigned*)hts)[(w * 4 + i) * 32 + m] = pack_f16(h0, h1);
    }
    __syncthreads();
    int quad = lane >> 4, m16 = lane & 15;
    if (w < 3) {
        h8 fa0 = *(const h8*)&hts[m16 * 64 + 0 + quad * 8];
        h8 fa1 = *(const h8*)&hts[m16 * 64 + 32 + quad * 8];
        h8 fb0 = *(const h8*)&pBc[(size_t)(0 * 3 + w) * 512 + lane * 8];
        h8 fb1 = *(const h8*)&pBc[(size_t)(1 * 3 + w) * 512 + lane * 8];
        f4 c = {0.f, 0.f, 0.f, 0.f};
        c = __builtin_amdgcn_mfma_f32_16x16x32_f16(fa0, fb0, c, 0, 0, 0);
        c = __builtin_amdgcn_mfma_f32_16x16x32_f16(fa1, fb1, c, 0, 0, 0);
        int n = w * 16 + m16;
        float bcv = (n < NC) ? bc[n] : 0.f;
#pragma unroll
        for (int r = 0; r < 4; ++r) {
            int mrow = quad * 4 + r;
            lg[mrow * 48 + n] = (n < NC) ? (c[r] + bcv) : -INFINITY;
        }
    }
    __syncthreads();
    int row_l = w * 4 + quad;
    int grow = tileRow + row_l;
    int id = m16;
    float v0 = lg[row_l * 48 + id];
    float v1 = lg[row_l * 48 + id + 16];
    float v2 = lg[row_l * 48 + id + 32];  // -inf for cols >= 40
    float mx = fmaxf(fmaxf(v0, v1), v2);
#pragma unroll
    for (int off = 8; off; off >>= 1) mx = fmaxf(mx, __shfl_xor(mx, off, 64));
    float s = expf(v0 - mx) + expf(v1 - mx) + ((id < 8) ? expf(v2 - mx) : 0.f);
#pragma unroll
    for (int off = 8; off; off >>= 1) s += __shfl_xor(s, off, 64);
    float ls = logf(s);
    if (grow < N) {
        out[(size_t)grow * NC + id] = v0 - mx - ls;
        out[(size_t)grow * NC + id + 16] = v1 - mx - ls;
        if (id < 8) out[(size_t)grow * NC + id + 32] = v2 - mx - ls;
    }
}

extern "C" void kernel_launch(void* const* d_in, const int* in_sizes, int n_in,
                              void* d_out, int out_size, void* d_ws, size_t ws_size,
                              hipStream_t stream) {
    const float* x  = (const float*)d_in[0];
    const int*   ei = (const int*)d_in[1];
    const float* W0 = (const float*)d_in[2];
    const float* b0 = (const float*)d_in[3];
    const float* W1 = (const float*)d_in[4];
    const float* b1 = (const float*)d_in[5];
    const float* W2 = (const float*)d_in[6];
    const float* b2 = (const float*)d_in[7];
    const float* Wc = (const float*)d_in[8];
    const float* bc = (const float*)d_in[9];
    float* out = (float*)d_out;

    const int N = in_sizes[0] / D;   // 100000
    const int E = in_sizes[1] / 2;   // 800000
    const int* src = ei;
    const int* dst = ei + E;

    char* ws = (char*)d_ws;
    float*         dinv    = (float*)(ws + 0);             // N*4
    int*           rowptr  = (int*)  (ws + 524288u);       // (N+1)*4
    int*           cursors = (int*)  (ws + 1048576u);      // NBUCK*4
    int*           col     = (int*)  (ws + 1310720u);      // E*4
    unsigned*      staging = (unsigned*)(ws + 5242880u);   // NBUCK*CAP*4
    __fp16*        pB0     = (__fp16*)(ws + 10485760u);    // 8 KB
    __fp16*        pB1     = (__fp16*)(ws + 10493952u);    // 8 KB
    __fp16*        pB2     = (__fp16*)(ws + 10502144u);    // 8 KB
    __fp16*        pBc     = (__fp16*)(ws + 10510336u);    // 6 KB
    unsigned char* A       = (unsigned char*)(ws + 16777216u);  // N*64 fp8 = 6.4 MB
    unsigned char* B       = (unsigned char*)(ws + 25165824u);  // N*64 fp8 = 6.4 MB

    const int BLK = 256;
    const int gT16  = (N + 15) / 16;
    const int gP1   = (E + CHUNK - 1) / CHUNK;

    pack_weights2<<<16, BLK, 0, stream>>>(W0, W1, W2, Wc, pB0, pB1, pB2, pBc, cursors);
    part1_kernel<<<gP1, BLK, 0, stream>>>(src, dst, E, staging, cursors);
    part2_kernel<<<NBUCK, BLK, 0, stream>>>(staging, cursors, rowptr, dinv, col, N, E);

    transform_mfma<<<gT16, BLK, 0, stream>>>(x, dinv, pB0, A, N);
    fused_layer_mfma<<<gT16, BLK, 0, stream>>>(A, rowptr, col, dinv, b0, pB1, B, N);
    fused_layer_mfma<<<gT16, BLK, 0, stream>>>(B, rowptr, col, dinv, b1, pB2, A, N);
    agg_head_mfma<<<gT16, BLK, 0, stream>>>(A, rowptr, col, dinv, b2, pBc, bc, out, N);
}